// Round 1
// baseline (431.004 us; speedup 1.0000x reference)
//
#include <hip/hip_runtime.h>

// KV cache update, token-gen path.
// Shapes: L=2, B=4, H=8, M=4096, D=128, fp32.
// out[2, L, B, H, M, D]: out[0]=k_caches, out[1]=v_caches, with row
// m == position_ids[b] replaced by latest_{k,v}[l,b,h,0,:] for every (l,b,h).
// Pure streaming copy (537 MB HBM traffic) + 128-row sparse overwrite, fused.
//
// Structure: each block owns 2048 consecutive float4 = 64 rows. Since
// 64 | 4096 (= M rows per (kv,l,b,h) slab), the whole block shares one
// (kv,l,b,h) -> decode + pos[b] + src select are block-uniform (SALU).
// Per thread: 8x float4 nontemporal copy (128 B in flight). Only the
// 64/8192 blocks containing the scatter row touch the compare path.

typedef float v4f __attribute__((ext_vector_type(4)));

constexpr int  Ln = 2, Bn = 4, Hn = 8, Mn = 4096, Dn = 128;
constexpr long N_ELEM  = (long)Ln * Bn * Hn * Mn * Dn;   // 33,554,432 per cache
constexpr long N_VEC   = N_ELEM / 4;                     // 8,388,608 float4 per cache
constexpr long TOT_VEC = 2 * N_VEC;                      // 16,777,216 float4 total

constexpr int  UNROLL        = 8;
constexpr int  BLOCK         = 256;
constexpr int  VEC_PER_BLOCK = BLOCK * UNROLL;           // 2048 float4 = 64 rows
constexpr long GRID          = TOT_VEC / VEC_PER_BLOCK;  // 8192 blocks, exact cover

__global__ __launch_bounds__(BLOCK) void kv_update_kernel(
    const v4f* __restrict__ kc,   // k_caches
    const v4f* __restrict__ vc,   // v_caches
    const v4f* __restrict__ lk,   // latest_k
    const v4f* __restrict__ lv,   // latest_v
    const int* __restrict__ pos,  // position_ids (B,1)
    v4f*       __restrict__ out)
{
    const long blockBase = (long)blockIdx.x * VEC_PER_BLOCK;

    // Block-uniform decode (SALU): row index = vec index >> 5 (32 float4/row).
    const long rowBase = blockBase >> 5;            // first of 64 rows, same slab
    const int  m0  = (int)(rowBase & (Mn - 1));     // block covers m0 .. m0+63
    const long t2  = rowBase >> 12;                 // M = 4096 rows
    const int  h   = (int)(t2 & (Hn - 1));          // H = 8
    const int  b   = (int)((t2 >> 3) & (Bn - 1));   // B = 4
    const int  l   = (int)((t2 >> 5) & 1);          // L = 2
    const int  kv  = (int)(t2 >> 6);                // 0 = k, 1 = v

    const v4f* __restrict__ src = kv ? vc : kc;
    const long srcBase = blockBase & (N_VEC - 1);   // offset within the cache half
    const int  tid = threadIdx.x;

    // Streaming read: 8 x 16 B per thread, all issued before any store.
    v4f vals[UNROLL];
#pragma unroll
    for (int u = 0; u < UNROLL; ++u)
        vals[u] = __builtin_nontemporal_load(&src[srcBase + tid + u * BLOCK]);

    // Sparse overwrite: pos[b] is block-uniform -> scalar load + uniform branch.
    const int p    = pos[b];
    const int prow = p - m0;                        // in [0,64) iff row is ours
    if ((unsigned)prow < 64u) {
        const v4f* lsrc = kv ? lv : lk;
        const v4f  lval = lsrc[((l * Bn + b) * Hn + h) * (Dn / 4) + (tid & 31)];
#pragma unroll
        for (int u = 0; u < UNROLL; ++u) {
            const int rowoff = (tid + u * BLOCK) >> 5;
            if (rowoff == prow) vals[u] = lval;
        }
    }

    // Streaming write, nontemporal (no reuse -> don't thrash L2).
#pragma unroll
    for (int u = 0; u < UNROLL; ++u)
        __builtin_nontemporal_store(vals[u], &out[blockBase + tid + u * BLOCK]);
}

extern "C" void kernel_launch(void* const* d_in, const int* in_sizes, int n_in,
                              void* d_out, int out_size, void* d_ws, size_t ws_size,
                              hipStream_t stream) {
    const v4f* kc  = (const v4f*)d_in[0];
    const v4f* vc  = (const v4f*)d_in[1];
    const v4f* lk  = (const v4f*)d_in[2];
    const v4f* lv  = (const v4f*)d_in[3];
    const int* pos = (const int*)d_in[4];
    // d_in[5] = seq_len (unused: position_ids < seq_len by construction,
    // and the scatter+concat is equivalent to a direct row overwrite).
    v4f* out = (v4f*)d_out;

    kv_update_kernel<<<dim3((unsigned)GRID), dim3(BLOCK), 0, stream>>>(
        kc, vc, lk, lv, pos, out);
}